// Round 15
// baseline (3443.925 us; speedup 1.0000x reference)
//
#include <hip/hip_runtime.h>
#include <hip/hip_bf16.h>
#include <cstddef>

namespace {

constexpr int B = 16, T = 32, S = 400, E = 128, H = 512, V = 32000, OOV = 50, VEXT = V + OOV;

typedef __attribute__((ext_vector_type(8))) short short8v;
typedef __attribute__((ext_vector_type(4))) float f32x4;

__device__ __forceinline__ float fsig(float x){ return 1.0f/(1.0f+__expf(-x)); }
__device__ __forceinline__ float ftanh(float x){
  float ax = fabsf(x);
  float t = __expf(-2.0f*ax);
  float r = (1.0f - t)/(1.0f + t);
  return copysignf(r, x);
}
__device__ __forceinline__ unsigned short f2bf(float f){   // round-to-nearest-even
  unsigned int u = __float_as_uint(f);
  unsigned int r = (u + 0x7FFFu + ((u >> 16) & 1u)) >> 16;
  return (unsigned short)r;
}
__device__ __forceinline__ float bf2f(unsigned short u){
  return __uint_as_float(((unsigned)u) << 16);
}

// grid-stride init: enc->bf16 copy; copy h0->harr[0], c0; zero cov, vsum.
__global__ __launch_bounds__(256) void k_init(const float* __restrict__ enc,
    const float* __restrict__ h0, const float* __restrict__ c0,
    unsigned short* __restrict__ enc_bf, float* __restrict__ harr,
    float* __restrict__ cbuf, float* __restrict__ cov, float* __restrict__ vsum){
  const int stride = gridDim.x*256;
  for (int i = blockIdx.x*256 + threadIdx.x; i < B*S*H; i += stride){
    enc_bf[i] = f2bf(enc[i]);
    if (i < B*H){ harr[i] = h0[i]; cbuf[i] = c0[i]; }
    if (i < B*S) cov[i] = 0.0f;
    if (i < T*B) vsum[i] = 0.0f;
  }
}

// x_all[0][b][j] = emb[b][0][:] . W_xctx[j][:E] + b_xctx[j]   (ctx_0 = 0)
__global__ __launch_bounds__(128) void k_x0(const float* __restrict__ emb,
    const float* __restrict__ W_xctx, const float* __restrict__ b_xctx,
    float* __restrict__ x0){
  const int b = blockIdx.x, tid = threadIdx.x;
  __shared__ float se[E];
  se[tid] = emb[(size_t)(b*T)*E + tid];
  __syncthreads();
  const float* w = W_xctx + (size_t)tid*(E+H);
  float acc = b_xctx[tid];
  #pragma unroll 8
  for (int k=0;k<E;k+=4){
    float4 wv = *reinterpret_cast<const float4*>(w+k);
    acc += se[k]*wv.x + se[k+1]*wv.y + se[k+2]*wv.z + se[k+3]*wv.w;
  }
  x0[b*E + tid] = acc;
}

// z=0: Wt[a][b] = W_energy[b][H+a]; z=1: WdT[a][b] = W_energy[b][a].
__global__ __launch_bounds__(256) void k_trw2(const float* __restrict__ W_energy,
    float* __restrict__ Wt, float* __restrict__ WdT){
  __shared__ float tile[32][33];
  const int z = blockIdx.z;
  float* out = z ? WdT : Wt;
  const int off = z ? 0 : H;
  const int j0 = blockIdx.x*32, k0 = blockIdx.y*32;
  const int tx = threadIdx.x & 31, ty = threadIdx.x >> 5;
  #pragma unroll
  for (int r=0;r<4;++r)
    tile[ty+8*r][tx] = W_energy[(size_t)(k0+ty+8*r)*(2*H) + off + j0 + tx];
  __syncthreads();
  #pragma unroll
  for (int r=0;r<4;++r)
    out[(size_t)(j0+ty+8*r)*H + k0 + tx] = tile[tx][ty+8*r];
}

// enc_proj (bf16 out): 400 blocks x 512 threads (k=tid).
__global__ __launch_bounds__(512) void k_encproj(const float* __restrict__ enc,
                          const float* __restrict__ Wt,
                          const float* __restrict__ b_energy,
                          unsigned short* __restrict__ enc_proj){
  const int r0 = blockIdx.x*16, k = threadIdx.x;
  const float* eb = enc + (size_t)r0*H;
  float acc[16];
  #pragma unroll
  for (int r=0;r<16;++r) acc[r]=0.0f;
  for (int j=0;j<H;j+=4){
    const float w0 = Wt[(size_t) j   *H + k];
    const float w1 = Wt[(size_t)(j+1)*H + k];
    const float w2 = Wt[(size_t)(j+2)*H + k];
    const float w3 = Wt[(size_t)(j+3)*H + k];
    #pragma unroll
    for (int r=0;r<16;++r){
      acc[r] += eb[(size_t)r*H + j]*w0 + eb[(size_t)r*H + j+1]*w1
              + eb[(size_t)r*H + j+2]*w2 + eb[(size_t)r*H + j+3]*w3;
    }
  }
  const float be = b_energy[k];
  #pragma unroll
  for (int r=0;r<16;++r) enc_proj[(size_t)(r0+r)*H + k] = f2bf(acc[r] + be);
}

// grid 256 x 256: gates partial GEMM -> gpart[kh][b][row].
__global__ __launch_bounds__(256) void k_gates2(
    const float* __restrict__ x, const float* __restrict__ hold,
    const float* __restrict__ W_ih, const float* __restrict__ W_hh,
    float* __restrict__ gpart){
  const int blk = blockIdx.x, tid = threadIdx.x;
  const int gbh = blk >> 2, kh = blk & 3;
  const int gb = gbh >> 1, bh = gbh & 1, b0 = bh*8;
  __shared__ float xh[8][640];
  __shared__ float sg[4][64][9];
  for (int b=0;b<8;++b)
    for (int k=tid;k<640;k+=256)
      xh[b][k] = (k<E) ? x[(b0+b)*E + k] : hold[(b0+b)*H + (k-E)];
  __syncthreads();
  const int w = tid >> 6, l = tid & 63, g = l >> 4, jj = l & 15;
  const int row = g*H + gb*16 + jj;
  float acc[8];
  #pragma unroll
  for (int b=0;b<8;++b) acc[b]=0.0f;
  const int ks = kh*160 + w*40, ke = ks + 40;
  const int k1 = (ke < 128) ? ke : 128;
  if (ks < 128){
    const float* wr = W_ih + (size_t)row*E;
    for (int k=ks; k<k1; k+=4){
      const float4 wv = *reinterpret_cast<const float4*>(wr + k);
      #pragma unroll
      for (int b=0;b<8;++b){
        const float4 xv = *reinterpret_cast<const float4*>(&xh[b][k]);
        acc[b] += xv.x*wv.x + xv.y*wv.y + xv.z*wv.z + xv.w*wv.w;
      }
    }
  }
  const int k2 = (ks > 128) ? ks : 128;
  if (k2 < ke){
    const float* wr = W_hh + (size_t)row*H - 128;   // wr[k] == W_hh[row][k-128]
    for (int k=k2; k<ke; k+=4){
      const float4 wv = *reinterpret_cast<const float4*>(wr + k);
      #pragma unroll
      for (int b=0;b<8;++b){
        const float4 xv = *reinterpret_cast<const float4*>(&xh[b][k]);
        acc[b] += xv.x*wv.x + xv.y*wv.y + xv.z*wv.z + xv.w*wv.w;
      }
    }
  }
  #pragma unroll
  for (int b=0;b<8;++b) sg[w][l][b] = acc[b];
  __syncthreads();
  for (int i=tid; i<512; i+=256){
    const int l2 = i & 63, b = i >> 6;
    const int g2 = l2 >> 4, j2 = l2 & 15;
    const int row2 = g2*H + gb*16 + j2;
    gpart[((size_t)kh*B + (b0+b))*(4*H) + row2] =
        sg[0][l2][b]+sg[1][l2][b]+sg[2][l2][b]+sg[3][l2][b];
  }
}

// grid (16 b, 4 sc) x 256: LSTM (x4 redundant, sc0 writes h/c + zeroes xnext)
// -> full dec GEMV (2 cols/thread, WdT L2-broadcast) -> 100 scores per block.
__global__ __launch_bounds__(256) void k_decscore(
    const float* __restrict__ gpart, const float* __restrict__ cold,
    const float* __restrict__ b_ih, const float* __restrict__ b_hh,
    const float* __restrict__ WdT, const unsigned short* __restrict__ encp,
    const float* __restrict__ W_cov, const float* __restrict__ v_attn,
    const float* __restrict__ cov,
    float* __restrict__ cnew, float* __restrict__ hnew,
    float* __restrict__ score, float* __restrict__ xnext){
  const int b = blockIdx.x, sc = blockIdx.y, tid = threadIdx.x;
  __shared__ float sh[H], sdec[H], swc[H], sva[H];
  // Phase 1: LSTM (2 j per thread)
  #pragma unroll
  for (int jj=0; jj<2; ++jj){
    const int j = tid + jj*256;
    float gs[4];
    #pragma unroll
    for (int g=0; g<4; ++g){
      const int row = g*H + j;
      float v = b_ih[row] + b_hh[row];
      #pragma unroll
      for (int kh=0; kh<4; ++kh) v += gpart[((size_t)kh*B + b)*(4*H) + row];
      gs[g] = v;
    }
    const float ig = fsig(gs[0]);
    const float fg = fsig(gs[1]);
    const float gg = ftanh(gs[2]);
    const float og = fsig(gs[3]);
    const float cn = fg*cold[b*H + j] + ig*gg;
    const float hn = og*ftanh(cn);
    if (sc==0){ cnew[b*H + j] = cn; hnew[b*H + j] = hn; }
    sh[j] = hn;
    swc[j] = W_cov[j];
    sva[j] = v_attn[j];
  }
  if (sc==0 && tid < E) xnext[b*E + tid] = 0.0f;
  __syncthreads();
  // Phase 2: dec GEMV, 2 cols per thread (coalesced WdT rows)
  {
    float a0 = 0.0f, a1 = 0.0f;
    const int j0 = tid, j1 = tid + 256;
    #pragma unroll 4
    for (int k=0; k<H; ++k){
      const float hv = sh[k];
      const float* wr = WdT + (size_t)k*H;
      a0 += hv*wr[j0];
      a1 += hv*wr[j1];
    }
    sdec[j0] = a0;
    sdec[j1] = a1;
  }
  __syncthreads();
  // Phase 3: scores for s in [sc*100, sc*100+100), wave per s
  {
    const int wid = tid >> 6, lane = tid & 63, k0 = lane*8;
    const int s0 = sc*100;
    for (int s = s0 + wid; s < s0 + 100; s += 4){
      const float cv = cov[b*S + s];
      const short8v ev = *reinterpret_cast<const short8v*>(
          encp + (size_t)(b*S + s)*H + k0);
      float a = 0.0f;
      #pragma unroll
      for (int u=0;u<8;++u){
        const int k = k0+u;
        a += ftanh(sdec[k] + bf2f((unsigned short)ev[u]) + cv*swc[k]) * sva[k];
      }
      #pragma unroll
      for (int off=32; off>0; off>>=1) a += __shfl_down(a, off);
      if (lane==0) score[b*S + s] = a;
    }
  }
}

// grid (16 b, 8 hc) x 256: softmax; ctx slice -> ctx_all; xnext split-K atomics.
__global__ __launch_bounds__(256) void k_ctx(const float* __restrict__ score,
    const float* __restrict__ masks, const unsigned short* __restrict__ enc_bf,
    const float* __restrict__ emb, int tnext,
    const float* __restrict__ W_xctx, const float* __restrict__ b_xctx,
    float* __restrict__ cov, float* __restrict__ probs_t,
    float* __restrict__ ctx_t, float* __restrict__ xnext){
  const int b = blockIdx.x, hc = blockIdx.y, tid = threadIdx.x;
  __shared__ float red[256], sp[512], sctx[64], se[E];
  if (tid < E) se[tid] = emb[(size_t)(b*T + tnext)*E + tid];
  const float sc0 = (tid < S)      ? score[b*S + tid]       : -1e30f;
  const float sc1 = (tid+256 < S)  ? score[b*S + tid + 256] : -1e30f;
  red[tid] = fmaxf(sc0, sc1);
  __syncthreads();
  for (int off=128; off>0; off>>=1){ if (tid<off) red[tid]=fmaxf(red[tid],red[tid+off]); __syncthreads(); }
  const float mx = red[0];
  __syncthreads();
  const float e0 = (tid < S)     ? __expf(sc0 - mx) : 0.0f;
  const float e1 = (tid+256 < S) ? __expf(sc1 - mx) : 0.0f;
  red[tid] = e0 + e1;
  __syncthreads();
  for (int off=128; off>0; off>>=1){ if (tid<off) red[tid]+=red[tid+off]; __syncthreads(); }
  const float den = red[0];
  __syncthreads();
  const float p0 = (tid < S)     ? (e0/den)*masks[b*S+tid]     : 0.0f;
  const float p1 = (tid+256 < S) ? (e1/den)*masks[b*S+tid+256] : 0.0f;
  red[tid] = p0 + p1;
  __syncthreads();
  for (int off=128; off>0; off>>=1){ if (tid<off) red[tid]+=red[tid+off]; __syncthreads(); }
  const float inv = 1.0f/(red[0] + 1e-12f);
  __syncthreads();
  const float pr0 = p0*inv, pr1 = p1*inv;
  sp[tid] = pr0; sp[tid+256] = pr1;
  if (hc==0){
    if (tid < S){ probs_t[b*S+tid] = pr0; cov[b*S+tid] += pr0; }
    if (tid+256 < S){ probs_t[b*S+tid+256] = pr1; cov[b*S+tid+256] += pr1; }
  }
  __syncthreads();
  {
    const int c = tid & 63, sg_ = tid >> 6;
    const unsigned short* eb = enc_bf + (size_t)b*S*H + hc*64 + c;
    float a = 0.0f;
    for (int s=sg_; s<S; s+=4) a += sp[s]*bf2f(eb[(size_t)s*H]);
    red[tid] = a;
    __syncthreads();
    if (tid < 64){
      const float cval = red[tid]+red[tid+64]+red[tid+128]+red[tid+192];
      sctx[tid] = cval;
      ctx_t[b*H + hc*64 + tid] = cval;
    }
  }
  __syncthreads();
  if (tid < E){
    const float* wr = W_xctx + (size_t)tid*(E+H);
    float acc = 0.0f;
    #pragma unroll
    for (int k=0;k<64;k+=4){
      const float4 wc = *reinterpret_cast<const float4*>(wr + E + hc*64 + k);
      acc += sctx[k]*wc.x + sctx[k+1]*wc.y + sctx[k+2]*wc.z + sctx[k+3]*wc.w;
    }
    #pragma unroll
    for (int k=0;k<16;k+=4){
      const float4 we = *reinterpret_cast<const float4*>(wr + hc*16 + k);
      const float* eb2 = se + hc*16 + k;
      acc += eb2[0]*we.x + eb2[1]*we.y + eb2[2]*we.z + eb2[3]*we.w;
    }
    if (hc==0) acc += b_xctx[tid];
    atomicAdd(&xnext[b*E + tid], acc);
  }
}

// MFMA GEMM: hh_all[m][n] = [h(m) | ctx(m)] . W_ad[n][:] + b_ad[n].
// M=512, N=512, K=1024. Grid (8 nt, 4 mt) x 512; block tile 128M x 64N;
// wave tile 64M x 16N (8 waves: wm=w>>2, wn=w&3).
__global__ __launch_bounds__(512) void k_hhgemm(const float* __restrict__ harr,
    const float* __restrict__ ctx_all, const float* __restrict__ W_ad,
    const float* __restrict__ b_ad, float* __restrict__ hh_all){
  __shared__ unsigned short ldsA[128][72];
  __shared__ unsigned short ldsB[64][72];
  const int tid = threadIdx.x, lane = tid & 63, w = tid >> 6;
  const int wm = w >> 2, wn = w & 3;
  const int m0 = (int)blockIdx.y * 128;
  const int n0 = (int)blockIdx.x * 64;
  const int nl = lane & 15, kg = lane >> 4;
  f32x4 acc[4];
  #pragma unroll
  for (int mf=0;mf<4;++mf) acc[mf] = (f32x4){0.f,0.f,0.f,0.f};
  for (int kc=0; kc<16; ++kc){
    __syncthreads();
    // stage A: 128 rows x 64 k (fp32 -> bf16)
    for (int j = tid; j < 2048; j += 512){
      const int row = j >> 4, c4 = j & 15;
      const int kk_ = kc*64 + c4*4;
      const float* src = (kk_ < H)
        ? (harr + (size_t)(m0+row+B)*H + kk_)
        : (ctx_all + (size_t)(m0+row)*H + (kk_ - H));
      const float4 v = *reinterpret_cast<const float4*>(src);
      ushort4 u; u.x=f2bf(v.x); u.y=f2bf(v.y); u.z=f2bf(v.z); u.w=f2bf(v.w);
      *reinterpret_cast<ushort4*>(&ldsA[row][c4*4]) = u;
    }
    // stage B: 64 rows x 64 k
    for (int j = tid; j < 1024; j += 512){
      const int row = j >> 4, c4 = j & 15;
      const float4 v = *reinterpret_cast<const float4*>(
          W_ad + (size_t)(n0+row)*(2*H) + kc*64 + c4*4);
      ushort4 u; u.x=f2bf(v.x); u.y=f2bf(v.y); u.z=f2bf(v.z); u.w=f2bf(v.w);
      *reinterpret_cast<ushort4*>(&ldsB[row][c4*4]) = u;
    }
    __syncthreads();
    #pragma unroll
    for (int kk=0; kk<2; ++kk){
      const short8v bfr = *reinterpret_cast<const short8v*>(&ldsB[wn*16 + nl][kk*32 + kg*8]);
      #pragma unroll
      for (int mf=0;mf<4;++mf){
        const short8v a = *reinterpret_cast<const short8v*>(&ldsA[wm*64 + mf*16 + nl][kk*32 + kg*8]);
        acc[mf] = __builtin_amdgcn_mfma_f32_16x16x32_bf16(a, bfr, acc[mf], 0, 0, 0);
      }
    }
  }
  const int n = n0 + wn*16 + nl;
  const float bv = b_ad[n];
  #pragma unroll
  for (int mf=0;mf<4;++mf){
    #pragma unroll
    for (int r=0;r<4;++r){
      const int m = m0 + wm*64 + mf*16 + kg*4 + r;
      hh_all[(size_t)m*H + n] = acc[mf][r] + bv;
    }
  }
}

// praw[m] = [ctx(m), h(m), x(m)] . W_pgen + b_pgen. grid 128 x 256 (one m/wave).
__global__ __launch_bounds__(256) void k_pgen(const float* __restrict__ ctx_all,
    const float* __restrict__ harr, const float* __restrict__ x_all,
    const float* __restrict__ W_pgen, const float* __restrict__ b_pgen,
    float* __restrict__ praw){
  const int m = blockIdx.x*4 + (threadIdx.x >> 6);
  const int lane = threadIdx.x & 63;
  float part = 0.0f;
  for (int k = lane; k < 2*H+E; k += 64){
    float v;
    if (k < H)        v = ctx_all[(size_t)m*H + k];
    else if (k < 2*H) v = harr[(size_t)(m+B)*H + (k-H)];
    else              v = x_all[(size_t)m*E + (k-2*H)];
    part += v * W_pgen[k];
  }
  #pragma unroll
  for (int off=32; off>0; off>>=1) part += __shfl_down(part, off);
  if (lane==0) praw[m] = part + b_pgen[0];
}

// Canonical LDS-tiled MFMA GEMM: out = exp(hh . W_vocab^T + b), rowsums -> vsum.
__global__ __launch_bounds__(512) void k_vocab3(
    const float* __restrict__ hh_all,
    const float* __restrict__ W_vocab, const float* __restrict__ b_vocab,
    float* __restrict__ out, float* __restrict__ vsum){
  __shared__ unsigned short ldsA[256][72];
  __shared__ unsigned short ldsB[128][72];
  __shared__ float svs[256];
  const int tid = threadIdx.x, lane = tid & 63, w = tid >> 6;
  const int wm = w >> 1, wn = w & 1;
  const int m0 = (int)blockIdx.y * 256;
  const int n0 = (int)blockIdx.x * 128;
  const int nl = lane & 15, kg = lane >> 4;
  if (tid < 256) svs[tid] = 0.0f;
  f32x4 acc[4][4];
  #pragma unroll
  for (int mf=0;mf<4;++mf)
    #pragma unroll
    for (int nf=0;nf<4;++nf) acc[mf][nf] = (f32x4){0.f,0.f,0.f,0.f};
  for (int kc=0; kc<8; ++kc){
    __syncthreads();
    for (int j = tid; j < 4096; j += 512){
      const int row = j >> 4, c4 = j & 15;
      const float4 v = *reinterpret_cast<const float4*>(
          hh_all + (size_t)(m0+row)*H + kc*64 + c4*4);
      ushort4 u; u.x=f2bf(v.x); u.y=f2bf(v.y); u.z=f2bf(v.z); u.w=f2bf(v.w);
      *reinterpret_cast<ushort4*>(&ldsA[row][c4*4]) = u;
    }
    for (int j = tid; j < 2048; j += 512){
      const int row = j >> 4, c4 = j & 15;
      const float4 v = *reinterpret_cast<const float4*>(
          W_vocab + (size_t)(n0+row)*H + kc*64 + c4*4);
      ushort4 u; u.x=f2bf(v.x); u.y=f2bf(v.y); u.z=f2bf(v.z); u.w=f2bf(v.w);
      *reinterpret_cast<ushort4*>(&ldsB[row][c4*4]) = u;
    }
    __syncthreads();
    #pragma unroll
    for (int kk=0; kk<2; ++kk){
      short8v a[4], bf[4];
      #pragma unroll
      for (int mf=0;mf<4;++mf)
        a[mf] = *reinterpret_cast<const short8v*>(&ldsA[wm*64 + mf*16 + nl][kk*32 + kg*8]);
      #pragma unroll
      for (int nf=0;nf<4;++nf)
        bf[nf] = *reinterpret_cast<const short8v*>(&ldsB[wn*64 + nf*16 + nl][kk*32 + kg*8]);
      #pragma unroll
      for (int mf=0;mf<4;++mf)
        #pragma unroll
        for (int nf=0;nf<4;++nf)
          acc[mf][nf] = __builtin_amdgcn_mfma_f32_16x16x32_bf16(a[mf], bf[nf], acc[mf][nf], 0, 0, 0);
    }
  }
  float bv[4];
  #pragma unroll
  for (int nf=0;nf<4;++nf) bv[nf] = b_vocab[n0 + wn*64 + nf*16 + nl];
  #pragma unroll
  for (int mf=0;mf<4;++mf){
    #pragma unroll
    for (int r=0;r<4;++r){
      const int m = m0 + wm*64 + mf*16 + kg*4 + r;   // m = t*16 + b
      const int tq = m >> 4, bq = m & 15;
      float* orow = out + ((size_t)bq*T + tq)*VEXT;
      float s = 0.0f;
      #pragma unroll
      for (int nf=0;nf<4;++nf){
        const int n = n0 + wn*64 + nf*16 + nl;
        const float e = __expf(acc[mf][nf][r] + bv[nf]);
        orow[n] = e;
        s += e;
      }
      s += __shfl_xor(s, 1);
      s += __shfl_xor(s, 2);
      s += __shfl_xor(s, 4);
      s += __shfl_xor(s, 8);
      if (nl == 0) atomicAdd(&svs[m - m0], s);
    }
  }
  __syncthreads();
  for (int i = tid; i < 256; i += 512) atomicAdd(&vsum[m0 + i], svs[i]);
}

__global__ __launch_bounds__(256) void k_finalize(const float* __restrict__ praw,
    const float* __restrict__ vsum, const float* __restrict__ exz,
    float* __restrict__ out){
  const int rm = blockIdx.x, vc = blockIdx.y, tid = threadIdx.x;
  const int t = rm >> 4, b = rm & 15;
  float* orow = out + ((size_t)b*T + t)*VEXT;
  if (vc < 8){
    const float scl = fsig(praw[rm]) / vsum[rm];
    const int base = vc*4000;
    for (int i = tid; i < 4000; i += 256) orow[base + i] *= scl;
  } else if (tid < OOV){
    orow[V + tid] = exz[b*OOV + tid];
  }
}

__global__ __launch_bounds__(256) void k_scatter_all(const float* __restrict__ probs_all,
    const float* __restrict__ praw, const int* __restrict__ eidx,
    float* __restrict__ out){
  const int stride = gridDim.x*256;
  for (int i = blockIdx.x*256 + threadIdx.x; i < T*B*S; i += stride){
    const int t = i / (B*S);
    const int rem = i - t*B*S;
    const int b = rem / S, s = rem - b*S;
    const float fac = 1.0f - fsig(praw[t*B + b]);
    float* orow = out + ((size_t)b*T + t)*VEXT;
    atomicAdd(&orow[eidx[b*S + s]], fac*probs_all[(size_t)(t*B + b)*S + s]);
  }
}

} // namespace

extern "C" void kernel_launch(void* const* d_in, const int* in_sizes, int n_in,
                              void* d_out, int out_size, void* d_ws, size_t ws_size,
                              hipStream_t stream){
  const float* emb    = (const float*)d_in[0];
  const float* h0     = (const float*)d_in[1];
  const float* c0     = (const float*)d_in[2];
  const float* enc    = (const float*)d_in[3];
  const float* masks  = (const float*)d_in[4];
  const float* exz    = (const float*)d_in[5];
  const int*   eidx   = (const int*)d_in[6];
  const float* W_ih   = (const float*)d_in[7];
  const float* W_hh   = (const float*)d_in[8];
  const float* b_ih   = (const float*)d_in[9];
  const float* b_hh   = (const float*)d_in[10];
  const float* W_vocab= (const float*)d_in[11];
  const float* b_vocab= (const float*)d_in[12];
  const float* W_cov  = (const float*)d_in[13];
  const float* W_energy=(const float*)d_in[14];
  const float* b_energy=(const float*)d_in[15];
  const float* v_attn = (const float*)d_in[16];
  const float* W_xctx = (const float*)d_in[17];
  const float* b_xctx = (const float*)d_in[18];
  const float* W_ad   = (const float*)d_in[19];
  const float* b_ad   = (const float*)d_in[20];
  const float* W_pgen = (const float*)d_in[21];
  const float* b_pgen = (const float*)d_in[22];

  float* ws = (float*)d_ws;
  float* cbuf     = ws;                 // 2 x 8192            -> 16384
  float* x_all    = ws + 16384;         // 33 x 2048 = 67584   -> 83968
  float* score    = ws + 83968;         // 6400                -> 90368
  float* cov      = ws + 90368;         // 6400                -> 96768
  float* praw     = ws + 96768;         // 512                 -> 97280
  float* vsum     = ws + 97280;         // 512                 -> 97792
  float* probs_all= ws + 97792;         // 204800              -> 302592
  float* harr     = ws + 302592;        // 33 x 8192 = 270336  -> 572928
  float* ctx_all  = ws + 572928;        // 262144              -> 835072
  float* hh_all   = ws + 835072;        // 262144              -> 1097216
  float* WdT      = ws + 1097216;       // 262144              -> 1359360
  float* Wt       = ws + 1359360;       // 262144              -> 1621504
  float* gpart    = ws + 1621504;       // 131072              -> 1752576
  unsigned short* enc_bf = (unsigned short*)(ws + 1752576);   // 3276800 u16
  unsigned short* encp   = (unsigned short*)(ws + 3390976);   // 3276800 u16
  float* outp     = (float*)d_out;

  k_init<<<300,256,0,stream>>>(enc,h0,c0,enc_bf,harr,cbuf,cov,vsum);
  k_x0<<<16,128,0,stream>>>(emb,W_xctx,b_xctx,x_all);
  k_trw2<<<dim3(16,16,2),256,0,stream>>>(W_energy,Wt,WdT);
  k_encproj<<<400,512,0,stream>>>(enc,Wt,b_energy,encp);

  for (int t=0;t<T;++t){
    const int p = t&1;
    const float* cold = cbuf + p*8192;
    float* cnew = cbuf + (p^1)*8192;
    const int tnext = (t+1 < T) ? (t+1) : (T-1);
    k_gates2<<<256,256,0,stream>>>(x_all + (size_t)t*B*E, harr + (size_t)t*B*H,
                                   W_ih, W_hh, gpart);
    k_decscore<<<dim3(16,4),256,0,stream>>>(gpart, cold, b_ih, b_hh, WdT, encp,
        W_cov, v_attn, cov, cnew, harr + (size_t)(t+1)*B*H, score,
        x_all + (size_t)(t+1)*B*E);
    k_ctx<<<dim3(16,8),256,0,stream>>>(score, masks, enc_bf, emb, tnext,
        W_xctx, b_xctx, cov, probs_all + (size_t)t*B*S,
        ctx_all + (size_t)t*B*H, x_all + (size_t)(t+1)*B*E);
  }

  k_hhgemm<<<dim3(8,4),512,0,stream>>>(harr, ctx_all, W_ad, b_ad, hh_all);
  k_pgen<<<128,256,0,stream>>>(ctx_all, harr, x_all, W_pgen, b_pgen, praw);
  k_vocab3<<<dim3(250,2),512,0,stream>>>(hh_all, W_vocab, b_vocab, outp, vsum);
  k_finalize<<<dim3(512,9),256,0,stream>>>(praw, vsum, exz, outp);
  k_scatter_all<<<200,256,0,stream>>>(probs_all, praw, eidx, outp);
}

// Round 16
// 2040.459 us; speedup vs baseline: 1.6878x; 1.6878x over previous
//
#include <hip/hip_runtime.h>
#include <hip/hip_bf16.h>
#include <cstddef>

namespace {

constexpr int B = 16, T = 32, S = 400, E = 128, H = 512, V = 32000, OOV = 50, VEXT = V + OOV;

typedef __attribute__((ext_vector_type(8))) short short8v;
typedef __attribute__((ext_vector_type(4))) float f32x4;

__device__ __forceinline__ float fsig(float x){ return 1.0f/(1.0f+__expf(-x)); }
__device__ __forceinline__ float ftanh(float x){
  float ax = fabsf(x);
  float t = __expf(-2.0f*ax);
  float r = (1.0f - t)/(1.0f + t);
  return copysignf(r, x);
}
__device__ __forceinline__ unsigned short f2bf(float f){   // round-to-nearest-even
  unsigned int u = __float_as_uint(f);
  unsigned int r = (u + 0x7FFFu + ((u >> 16) & 1u)) >> 16;
  return (unsigned short)r;
}
__device__ __forceinline__ float bf2f(unsigned short u){
  return __uint_as_float(((unsigned)u) << 16);
}

// grid-stride init: enc->bf16 copy; copy h0->harr[0], c0; zero cov, vsum.
__global__ __launch_bounds__(256) void k_init(const float* __restrict__ enc,
    const float* __restrict__ h0, const float* __restrict__ c0,
    unsigned short* __restrict__ enc_bf, float* __restrict__ harr,
    float* __restrict__ cbuf, float* __restrict__ cov, float* __restrict__ vsum){
  const int stride = gridDim.x*256;
  for (int i = blockIdx.x*256 + threadIdx.x; i < B*S*H; i += stride){
    enc_bf[i] = f2bf(enc[i]);
    if (i < B*H){ harr[i] = h0[i]; cbuf[i] = c0[i]; }
    if (i < B*S) cov[i] = 0.0f;
    if (i < T*B) vsum[i] = 0.0f;
  }
}

// x_all[0][b][j] = emb[b][0][:] . W_xctx[j][:E] + b_xctx[j]   (ctx_0 = 0)
__global__ __launch_bounds__(128) void k_x0(const float* __restrict__ emb,
    const float* __restrict__ W_xctx, const float* __restrict__ b_xctx,
    float* __restrict__ x0){
  const int b = blockIdx.x, tid = threadIdx.x;
  __shared__ float se[E];
  se[tid] = emb[(size_t)(b*T)*E + tid];
  __syncthreads();
  const float* w = W_xctx + (size_t)tid*(E+H);
  float acc = b_xctx[tid];
  #pragma unroll 8
  for (int k=0;k<E;k+=4){
    float4 wv = *reinterpret_cast<const float4*>(w+k);
    acc += se[k]*wv.x + se[k+1]*wv.y + se[k+2]*wv.z + se[k+3]*wv.w;
  }
  x0[b*E + tid] = acc;
}

// z=0: Wt[a][b] = W_energy[b][H+a]; z=1: WdT[a][b] = W_energy[b][a].
__global__ __launch_bounds__(256) void k_trw2(const float* __restrict__ W_energy,
    float* __restrict__ Wt, float* __restrict__ WdT){
  __shared__ float tile[32][33];
  const int z = blockIdx.z;
  float* out = z ? WdT : Wt;
  const int off = z ? 0 : H;
  const int j0 = blockIdx.x*32, k0 = blockIdx.y*32;
  const int tx = threadIdx.x & 31, ty = threadIdx.x >> 5;
  #pragma unroll
  for (int r=0;r<4;++r)
    tile[ty+8*r][tx] = W_energy[(size_t)(k0+ty+8*r)*(2*H) + off + j0 + tx];
  __syncthreads();
  #pragma unroll
  for (int r=0;r<4;++r)
    out[(size_t)(j0+ty+8*r)*H + k0 + tx] = tile[tx][ty+8*r];
}

// enc_proj (bf16 out): 400 blocks x 512 threads (k=tid).
__global__ __launch_bounds__(512) void k_encproj(const float* __restrict__ enc,
                          const float* __restrict__ Wt,
                          const float* __restrict__ b_energy,
                          unsigned short* __restrict__ enc_proj){
  const int r0 = blockIdx.x*16, k = threadIdx.x;
  const float* eb = enc + (size_t)r0*H;
  float acc[16];
  #pragma unroll
  for (int r=0;r<16;++r) acc[r]=0.0f;
  for (int j=0;j<H;j+=4){
    const float w0 = Wt[(size_t) j   *H + k];
    const float w1 = Wt[(size_t)(j+1)*H + k];
    const float w2 = Wt[(size_t)(j+2)*H + k];
    const float w3 = Wt[(size_t)(j+3)*H + k];
    #pragma unroll
    for (int r=0;r<16;++r){
      acc[r] += eb[(size_t)r*H + j]*w0 + eb[(size_t)r*H + j+1]*w1
              + eb[(size_t)r*H + j+2]*w2 + eb[(size_t)r*H + j+3]*w3;
    }
  }
  const float be = b_energy[k];
  #pragma unroll
  for (int r=0;r<16;++r) enc_proj[(size_t)(r0+r)*H + k] = f2bf(acc[r] + be);
}

// grid 256 x 256: gates partial GEMM -> gpart[kh][b][row].
__global__ __launch_bounds__(256) void k_gates2(
    const float* __restrict__ x, const float* __restrict__ hold,
    const float* __restrict__ W_ih, const float* __restrict__ W_hh,
    float* __restrict__ gpart){
  const int blk = blockIdx.x, tid = threadIdx.x;
  const int gbh = blk >> 2, kh = blk & 3;
  const int gb = gbh >> 1, bh = gbh & 1, b0 = bh*8;
  __shared__ float xh[8][640];
  __shared__ float sg[4][64][9];
  for (int b=0;b<8;++b)
    for (int k=tid;k<640;k+=256)
      xh[b][k] = (k<E) ? x[(b0+b)*E + k] : hold[(b0+b)*H + (k-E)];
  __syncthreads();
  const int w = tid >> 6, l = tid & 63, g = l >> 4, jj = l & 15;
  const int row = g*H + gb*16 + jj;
  float acc[8];
  #pragma unroll
  for (int b=0;b<8;++b) acc[b]=0.0f;
  const int ks = kh*160 + w*40, ke = ks + 40;
  const int k1 = (ke < 128) ? ke : 128;
  if (ks < 128){
    const float* wr = W_ih + (size_t)row*E;
    for (int k=ks; k<k1; k+=4){
      const float4 wv = *reinterpret_cast<const float4*>(wr + k);
      #pragma unroll
      for (int b=0;b<8;++b){
        const float4 xv = *reinterpret_cast<const float4*>(&xh[b][k]);
        acc[b] += xv.x*wv.x + xv.y*wv.y + xv.z*wv.z + xv.w*wv.w;
      }
    }
  }
  const int k2 = (ks > 128) ? ks : 128;
  if (k2 < ke){
    const float* wr = W_hh + (size_t)row*H - 128;   // wr[k] == W_hh[row][k-128]
    for (int k=k2; k<ke; k+=4){
      const float4 wv = *reinterpret_cast<const float4*>(wr + k);
      #pragma unroll
      for (int b=0;b<8;++b){
        const float4 xv = *reinterpret_cast<const float4*>(&xh[b][k]);
        acc[b] += xv.x*wv.x + xv.y*wv.y + xv.z*wv.z + xv.w*wv.w;
      }
    }
  }
  #pragma unroll
  for (int b=0;b<8;++b) sg[w][l][b] = acc[b];
  __syncthreads();
  for (int i=tid; i<512; i+=256){
    const int l2 = i & 63, b = i >> 6;
    const int g2 = l2 >> 4, j2 = l2 & 15;
    const int row2 = g2*H + gb*16 + j2;
    gpart[((size_t)kh*B + (b0+b))*(4*H) + row2] =
        sg[0][l2][b]+sg[1][l2][b]+sg[2][l2][b]+sg[3][l2][b];
  }
}

// grid 64 x 256: LSTM from gpart (dup-write x8, benign) + dec GEMV slice.
__global__ __launch_bounds__(256) void k_dec2(const float* __restrict__ gpart,
    const float* __restrict__ cold, const float* __restrict__ b_ih,
    const float* __restrict__ b_hh, const float* __restrict__ WdT,
    float* __restrict__ cnew, float* __restrict__ hnew, float* __restrict__ dec){
  const int blk = blockIdx.x, tid = threadIdx.x;
  const int jc = blk >> 3, bp = blk & 7, b0 = bp*2;
  __shared__ float sh[2][H];
  __shared__ float r[4][64][2];
  for (int i=tid; i<2*H; i+=256){
    const int bl = i >> 9, j = i & 511;
    const int b = b0 + bl;
    float gs[4];
    #pragma unroll
    for (int g=0; g<4; ++g){
      const int row = g*H + j;
      float v = b_ih[row] + b_hh[row];
      #pragma unroll
      for (int kh=0; kh<4; ++kh) v += gpart[((size_t)kh*B + b)*(4*H) + row];
      gs[g] = v;
    }
    const float ig = fsig(gs[0]);
    const float fg = fsig(gs[1]);
    const float gg = ftanh(gs[2]);
    const float og = fsig(gs[3]);
    const float cn = fg*cold[b*H + j] + ig*gg;
    const float hn = og*ftanh(cn);
    cnew[b*H + j] = cn;
    hnew[b*H + j] = hn;
    sh[bl][j] = hn;
  }
  __syncthreads();
  const int w = tid >> 6, lane = tid & 63;
  const int j = jc*64 + lane;
  float a0=0.0f, a1=0.0f;
  for (int k=w*128; k<w*128+128; ++k){
    const float wv = WdT[(size_t)k*H + j];
    a0 += sh[0][k]*wv;
    a1 += sh[1][k]*wv;
  }
  r[w][lane][0]=a0; r[w][lane][1]=a1;
  __syncthreads();
  if (tid < 128){
    const int jl = tid & 63, bb = tid >> 6;
    dec[(b0+bb)*H + jc*64 + jl] = r[0][jl][bb]+r[1][jl][bb]+r[2][jl][bb]+r[3][jl][bb];
  }
}

// grid (100, B): one (b,s) per wave; bf16 encp. blockIdx.x==0 zeroes xnext.
__global__ __launch_bounds__(256) void k_score(const float* __restrict__ dec_proj,
    const unsigned short* __restrict__ encp, const float* __restrict__ W_cov,
    const float* __restrict__ v_attn, const float* __restrict__ cov,
    float* __restrict__ score, float* __restrict__ xnext){
  const int b = blockIdx.y;
  if (blockIdx.x==0 && threadIdx.x < E) xnext[b*E + threadIdx.x] = 0.0f;
  const int wave = threadIdx.x >> 6, lane = threadIdx.x & 63;
  const int s = blockIdx.x*4 + wave;
  const float cv = cov[b*S + s];
  const int k0 = lane*8;
  const short8v ev = *reinterpret_cast<const short8v*>(encp + (size_t)(b*S + s)*H + k0);
  const float* dp = dec_proj + b*H;
  float acc = 0.0f;
  #pragma unroll
  for (int u=0;u<8;++u){
    const int k = k0+u;
    acc += ftanh(dp[k] + bf2f((unsigned short)ev[u]) + cv*W_cov[k]) * v_attn[k];
  }
  #pragma unroll
  for (int off=32; off>0; off>>=1) acc += __shfl_down(acc, off);
  if (lane==0) score[b*S + s] = acc;
}

// grid (16 b, 8 hc) x 256: softmax; ctx slice -> ctx_all; xnext split-K atomics.
__global__ __launch_bounds__(256) void k_ctx(const float* __restrict__ score,
    const float* __restrict__ masks, const unsigned short* __restrict__ enc_bf,
    const float* __restrict__ emb, int tnext,
    const float* __restrict__ W_xctx, const float* __restrict__ b_xctx,
    float* __restrict__ cov, float* __restrict__ probs_t,
    float* __restrict__ ctx_t, float* __restrict__ xnext){
  const int b = blockIdx.x, hc = blockIdx.y, tid = threadIdx.x;
  __shared__ float red[256], sp[512], sctx[64], se[E];
  if (tid < E) se[tid] = emb[(size_t)(b*T + tnext)*E + tid];
  const float sc0 = (tid < S)      ? score[b*S + tid]       : -1e30f;
  const float sc1 = (tid+256 < S)  ? score[b*S + tid + 256] : -1e30f;
  red[tid] = fmaxf(sc0, sc1);
  __syncthreads();
  for (int off=128; off>0; off>>=1){ if (tid<off) red[tid]=fmaxf(red[tid],red[tid+off]); __syncthreads(); }
  const float mx = red[0];
  __syncthreads();
  const float e0 = (tid < S)     ? __expf(sc0 - mx) : 0.0f;
  const float e1 = (tid+256 < S) ? __expf(sc1 - mx) : 0.0f;
  red[tid] = e0 + e1;
  __syncthreads();
  for (int off=128; off>0; off>>=1){ if (tid<off) red[tid]+=red[tid+off]; __syncthreads(); }
  const float den = red[0];
  __syncthreads();
  const float p0 = (tid < S)     ? (e0/den)*masks[b*S+tid]     : 0.0f;
  const float p1 = (tid+256 < S) ? (e1/den)*masks[b*S+tid+256] : 0.0f;
  red[tid] = p0 + p1;
  __syncthreads();
  for (int off=128; off>0; off>>=1){ if (tid<off) red[tid]+=red[tid+off]; __syncthreads(); }
  const float inv = 1.0f/(red[0] + 1e-12f);
  __syncthreads();
  const float pr0 = p0*inv, pr1 = p1*inv;
  sp[tid] = pr0; sp[tid+256] = pr1;
  if (hc==0){
    if (tid < S){ probs_t[b*S+tid] = pr0; cov[b*S+tid] += pr0; }
    if (tid+256 < S){ probs_t[b*S+tid+256] = pr1; cov[b*S+tid+256] += pr1; }
  }
  __syncthreads();
  {
    const int c = tid & 63, sg_ = tid >> 6;
    const unsigned short* eb = enc_bf + (size_t)b*S*H + hc*64 + c;
    float a = 0.0f;
    for (int s=sg_; s<S; s+=4) a += sp[s]*bf2f(eb[(size_t)s*H]);
    red[tid] = a;
    __syncthreads();
    if (tid < 64){
      const float cval = red[tid]+red[tid+64]+red[tid+128]+red[tid+192];
      sctx[tid] = cval;
      ctx_t[b*H + hc*64 + tid] = cval;
    }
  }
  __syncthreads();
  if (tid < E){
    const float* wr = W_xctx + (size_t)tid*(E+H);
    float acc = 0.0f;
    #pragma unroll
    for (int k=0;k<64;k+=4){
      const float4 wc = *reinterpret_cast<const float4*>(wr + E + hc*64 + k);
      acc += sctx[k]*wc.x + sctx[k+1]*wc.y + sctx[k+2]*wc.z + sctx[k+3]*wc.w;
    }
    #pragma unroll
    for (int k=0;k<16;k+=4){
      const float4 we = *reinterpret_cast<const float4*>(wr + hc*16 + k);
      const float* eb2 = se + hc*16 + k;
      acc += eb2[0]*we.x + eb2[1]*we.y + eb2[2]*we.z + eb2[3]*we.w;
    }
    if (hc==0) acc += b_xctx[tid];
    atomicAdd(&xnext[b*E + tid], acc);
  }
}

// MFMA GEMM: hh_all[m][n] = [h(m) | ctx(m)] . W_ad[n][:] + b_ad[n].
// M=512, N=512, K=1024. Grid (8 nt, 4 mt) x 512; block tile 128M x 64N;
// wave tile 64M x 16N (8 waves: wm=w>>2, wn=w&3).  [verified in round-15 run]
__global__ __launch_bounds__(512) void k_hhgemm(const float* __restrict__ harr,
    const float* __restrict__ ctx_all, const float* __restrict__ W_ad,
    const float* __restrict__ b_ad, float* __restrict__ hh_all){
  __shared__ unsigned short ldsA[128][72];
  __shared__ unsigned short ldsB[64][72];
  const int tid = threadIdx.x, lane = tid & 63, w = tid >> 6;
  const int wm = w >> 2, wn = w & 3;
  const int m0 = (int)blockIdx.y * 128;
  const int n0 = (int)blockIdx.x * 64;
  const int nl = lane & 15, kg = lane >> 4;
  f32x4 acc[4];
  #pragma unroll
  for (int mf=0;mf<4;++mf) acc[mf] = (f32x4){0.f,0.f,0.f,0.f};
  for (int kc=0; kc<16; ++kc){
    __syncthreads();
    for (int j = tid; j < 2048; j += 512){
      const int row = j >> 4, c4 = j & 15;
      const int kk_ = kc*64 + c4*4;
      const float* src = (kk_ < H)
        ? (harr + (size_t)(m0+row+B)*H + kk_)
        : (ctx_all + (size_t)(m0+row)*H + (kk_ - H));
      const float4 v = *reinterpret_cast<const float4*>(src);
      ushort4 u; u.x=f2bf(v.x); u.y=f2bf(v.y); u.z=f2bf(v.z); u.w=f2bf(v.w);
      *reinterpret_cast<ushort4*>(&ldsA[row][c4*4]) = u;
    }
    for (int j = tid; j < 1024; j += 512){
      const int row = j >> 4, c4 = j & 15;
      const float4 v = *reinterpret_cast<const float4*>(
          W_ad + (size_t)(n0+row)*(2*H) + kc*64 + c4*4);
      ushort4 u; u.x=f2bf(v.x); u.y=f2bf(v.y); u.z=f2bf(v.z); u.w=f2bf(v.w);
      *reinterpret_cast<ushort4*>(&ldsB[row][c4*4]) = u;
    }
    __syncthreads();
    #pragma unroll
    for (int kk=0; kk<2; ++kk){
      const short8v bfr = *reinterpret_cast<const short8v*>(&ldsB[wn*16 + nl][kk*32 + kg*8]);
      #pragma unroll
      for (int mf=0;mf<4;++mf){
        const short8v a = *reinterpret_cast<const short8v*>(&ldsA[wm*64 + mf*16 + nl][kk*32 + kg*8]);
        acc[mf] = __builtin_amdgcn_mfma_f32_16x16x32_bf16(a, bfr, acc[mf], 0, 0, 0);
      }
    }
  }
  const int n = n0 + wn*16 + nl;
  const float bv = b_ad[n];
  #pragma unroll
  for (int mf=0;mf<4;++mf){
    #pragma unroll
    for (int r=0;r<4;++r){
      const int m = m0 + wm*64 + mf*16 + kg*4 + r;
      hh_all[(size_t)m*H + n] = acc[mf][r] + bv;
    }
  }
}

// praw[m] = [ctx(m), h(m), x(m)] . W_pgen + b_pgen. grid 128 x 256 (one m/wave).
__global__ __launch_bounds__(256) void k_pgen(const float* __restrict__ ctx_all,
    const float* __restrict__ harr, const float* __restrict__ x_all,
    const float* __restrict__ W_pgen, const float* __restrict__ b_pgen,
    float* __restrict__ praw){
  const int m = blockIdx.x*4 + (threadIdx.x >> 6);
  const int lane = threadIdx.x & 63;
  float part = 0.0f;
  for (int k = lane; k < 2*H+E; k += 64){
    float v;
    if (k < H)        v = ctx_all[(size_t)m*H + k];
    else if (k < 2*H) v = harr[(size_t)(m+B)*H + (k-H)];
    else              v = x_all[(size_t)m*E + (k-2*H)];
    part += v * W_pgen[k];
  }
  #pragma unroll
  for (int off=32; off>0; off>>=1) part += __shfl_down(part, off);
  if (lane==0) praw[m] = part + b_pgen[0];
}

// Canonical LDS-tiled MFMA GEMM: out = exp(hh . W_vocab^T + b), rowsums -> vsum.
__global__ __launch_bounds__(512) void k_vocab3(
    const float* __restrict__ hh_all,
    const float* __restrict__ W_vocab, const float* __restrict__ b_vocab,
    float* __restrict__ out, float* __restrict__ vsum){
  __shared__ unsigned short ldsA[256][72];
  __shared__ unsigned short ldsB[128][72];
  __shared__ float svs[256];
  const int tid = threadIdx.x, lane = tid & 63, w = tid >> 6;
  const int wm = w >> 1, wn = w & 1;
  const int m0 = (int)blockIdx.y * 256;
  const int n0 = (int)blockIdx.x * 128;
  const int nl = lane & 15, kg = lane >> 4;
  if (tid < 256) svs[tid] = 0.0f;
  f32x4 acc[4][4];
  #pragma unroll
  for (int mf=0;mf<4;++mf)
    #pragma unroll
    for (int nf=0;nf<4;++nf) acc[mf][nf] = (f32x4){0.f,0.f,0.f,0.f};
  for (int kc=0; kc<8; ++kc){
    __syncthreads();
    for (int j = tid; j < 4096; j += 512){
      const int row = j >> 4, c4 = j & 15;
      const float4 v = *reinterpret_cast<const float4*>(
          hh_all + (size_t)(m0+row)*H + kc*64 + c4*4);
      ushort4 u; u.x=f2bf(v.x); u.y=f2bf(v.y); u.z=f2bf(v.z); u.w=f2bf(v.w);
      *reinterpret_cast<ushort4*>(&ldsA[row][c4*4]) = u;
    }
    for (int j = tid; j < 2048; j += 512){
      const int row = j >> 4, c4 = j & 15;
      const float4 v = *reinterpret_cast<const float4*>(
          W_vocab + (size_t)(n0+row)*H + kc*64 + c4*4);
      ushort4 u; u.x=f2bf(v.x); u.y=f2bf(v.y); u.z=f2bf(v.z); u.w=f2bf(v.w);
      *reinterpret_cast<ushort4*>(&ldsB[row][c4*4]) = u;
    }
    __syncthreads();
    #pragma unroll
    for (int kk=0; kk<2; ++kk){
      short8v a[4], bf[4];
      #pragma unroll
      for (int mf=0;mf<4;++mf)
        a[mf] = *reinterpret_cast<const short8v*>(&ldsA[wm*64 + mf*16 + nl][kk*32 + kg*8]);
      #pragma unroll
      for (int nf=0;nf<4;++nf)
        bf[nf] = *reinterpret_cast<const short8v*>(&ldsB[wn*64 + nf*16 + nl][kk*32 + kg*8]);
      #pragma unroll
      for (int mf=0;mf<4;++mf)
        #pragma unroll
        for (int nf=0;nf<4;++nf)
          acc[mf][nf] = __builtin_amdgcn_mfma_f32_16x16x32_bf16(a[mf], bf[nf], acc[mf][nf], 0, 0, 0);
    }
  }
  float bv[4];
  #pragma unroll
  for (int nf=0;nf<4;++nf) bv[nf] = b_vocab[n0 + wn*64 + nf*16 + nl];
  #pragma unroll
  for (int mf=0;mf<4;++mf){
    #pragma unroll
    for (int r=0;r<4;++r){
      const int m = m0 + wm*64 + mf*16 + kg*4 + r;   // m = t*16 + b
      const int tq = m >> 4, bq = m & 15;
      float* orow = out + ((size_t)bq*T + tq)*VEXT;
      float s = 0.0f;
      #pragma unroll
      for (int nf=0;nf<4;++nf){
        const int n = n0 + wn*64 + nf*16 + nl;
        const float e = __expf(acc[mf][nf][r] + bv[nf]);
        orow[n] = e;
        s += e;
      }
      s += __shfl_xor(s, 1);
      s += __shfl_xor(s, 2);
      s += __shfl_xor(s, 4);
      s += __shfl_xor(s, 8);
      if (nl == 0) atomicAdd(&svs[m - m0], s);
    }
  }
  __syncthreads();
  for (int i = tid; i < 256; i += 512) atomicAdd(&vsum[m0 + i], svs[i]);
}

__global__ __launch_bounds__(256) void k_finalize(const float* __restrict__ praw,
    const float* __restrict__ vsum, const float* __restrict__ exz,
    float* __restrict__ out){
  const int rm = blockIdx.x, vc = blockIdx.y, tid = threadIdx.x;
  const int t = rm >> 4, b = rm & 15;
  float* orow = out + ((size_t)b*T + t)*VEXT;
  if (vc < 8){
    const float scl = fsig(praw[rm]) / vsum[rm];
    const int base = vc*4000;
    for (int i = tid; i < 4000; i += 256) orow[base + i] *= scl;
  } else if (tid < OOV){
    orow[V + tid] = exz[b*OOV + tid];
  }
}

__global__ __launch_bounds__(256) void k_scatter_all(const float* __restrict__ probs_all,
    const float* __restrict__ praw, const int* __restrict__ eidx,
    float* __restrict__ out){
  const int stride = gridDim.x*256;
  for (int i = blockIdx.x*256 + threadIdx.x; i < T*B*S; i += stride){
    const int t = i / (B*S);
    const int rem = i - t*B*S;
    const int b = rem / S, s = rem - b*S;
    const float fac = 1.0f - fsig(praw[t*B + b]);
    float* orow = out + ((size_t)b*T + t)*VEXT;
    atomicAdd(&orow[eidx[b*S + s]], fac*probs_all[(size_t)(t*B + b)*S + s]);
  }
}

} // namespace

extern "C" void kernel_launch(void* const* d_in, const int* in_sizes, int n_in,
                              void* d_out, int out_size, void* d_ws, size_t ws_size,
                              hipStream_t stream){
  const float* emb    = (const float*)d_in[0];
  const float* h0     = (const float*)d_in[1];
  const float* c0     = (const float*)d_in[2];
  const float* enc    = (const float*)d_in[3];
  const float* masks  = (const float*)d_in[4];
  const float* exz    = (const float*)d_in[5];
  const int*   eidx   = (const int*)d_in[6];
  const float* W_ih   = (const float*)d_in[7];
  const float* W_hh   = (const float*)d_in[8];
  const float* b_ih   = (const float*)d_in[9];
  const float* b_hh   = (const float*)d_in[10];
  const float* W_vocab= (const float*)d_in[11];
  const float* b_vocab= (const float*)d_in[12];
  const float* W_cov  = (const float*)d_in[13];
  const float* W_energy=(const float*)d_in[14];
  const float* b_energy=(const float*)d_in[15];
  const float* v_attn = (const float*)d_in[16];
  const float* W_xctx = (const float*)d_in[17];
  const float* b_xctx = (const float*)d_in[18];
  const float* W_ad   = (const float*)d_in[19];
  const float* b_ad   = (const float*)d_in[20];
  const float* W_pgen = (const float*)d_in[21];
  const float* b_pgen = (const float*)d_in[22];

  float* ws = (float*)d_ws;
  float* cbuf     = ws;                 // 2 x 8192            -> 16384
  float* x_all    = ws + 16384;         // 33 x 2048 = 67584   -> 83968
  float* dec      = ws + 83968;         // 8192                -> 92160
  float* score    = ws + 92160;         // 6400                -> 98560
  float* cov      = ws + 98560;         // 6400                -> 104960
  float* praw     = ws + 104960;        // 512                 -> 105472
  float* vsum     = ws + 105472;        // 512                 -> 105984
  float* probs_all= ws + 105984;        // 204800              -> 310784
  float* harr     = ws + 310784;        // 33 x 8192 = 270336  -> 581120
  float* ctx_all  = ws + 581120;        // 262144              -> 843264
  float* hh_all   = ws + 843264;        // 262144              -> 1105408
  float* WdT      = ws + 1105408;       // 262144              -> 1367552
  float* Wt       = ws + 1367552;       // 262144              -> 1629696
  float* gpart    = ws + 1629696;       // 131072              -> 1760768
  unsigned short* enc_bf = (unsigned short*)(ws + 1760768);   // 3276800 u16
  unsigned short* encp   = (unsigned short*)(ws + 3399168);   // 3276800 u16
  float* outp     = (float*)d_out;

  k_init<<<300,256,0,stream>>>(enc,h0,c0,enc_bf,harr,cbuf,cov,vsum);
  k_x0<<<16,128,0,stream>>>(emb,W_xctx,b_xctx,x_all);
  k_trw2<<<dim3(16,16,2),256,0,stream>>>(W_energy,Wt,WdT);
  k_encproj<<<400,512,0,stream>>>(enc,Wt,b_energy,encp);

  for (int t=0;t<T;++t){
    const int p = t&1;
    const float* cold = cbuf + p*8192;
    float* cnew = cbuf + (p^1)*8192;
    const int tnext = (t+1 < T) ? (t+1) : (T-1);
    k_gates2<<<256,256,0,stream>>>(x_all + (size_t)t*B*E, harr + (size_t)t*B*H,
                                   W_ih, W_hh, gpart);
    k_dec2<<<64,256,0,stream>>>(gpart, cold, b_ih, b_hh, WdT,
                                cnew, harr + (size_t)(t+1)*B*H, dec);
    k_score<<<dim3(100,16),256,0,stream>>>(dec, encp, W_cov, v_attn, cov, score,
                                           x_all + (size_t)(t+1)*B*E);
    k_ctx<<<dim3(16,8),256,0,stream>>>(score, masks, enc_bf, emb, tnext,
        W_xctx, b_xctx, cov, probs_all + (size_t)t*B*S,
        ctx_all + (size_t)t*B*H, x_all + (size_t)(t+1)*B*E);
  }

  k_hhgemm<<<dim3(8,4),512,0,stream>>>(harr, ctx_all, W_ad, b_ad, hh_all);
  k_pgen<<<128,256,0,stream>>>(ctx_all, harr, x_all, W_pgen, b_pgen, praw);
  k_vocab3<<<dim3(250,2),512,0,stream>>>(hh_all, W_vocab, b_vocab, outp, vsum);
  k_finalize<<<dim3(512,9),256,0,stream>>>(praw, vsum, exz, outp);
  k_scatter_all<<<200,256,0,stream>>>(probs_all, praw, eidx, outp);
}

// Round 17
// 1998.887 us; speedup vs baseline: 1.7229x; 1.0208x over previous
//
#include <hip/hip_runtime.h>
#include <hip/hip_bf16.h>
#include <cstddef>

namespace {

constexpr int B = 16, T = 32, S = 400, E = 128, H = 512, V = 32000, OOV = 50, VEXT = V + OOV;

typedef __attribute__((ext_vector_type(8))) short short8v;
typedef __attribute__((ext_vector_type(4))) float f32x4;

__device__ __forceinline__ float fsig(float x){ return 1.0f/(1.0f+__expf(-x)); }
__device__ __forceinline__ float ftanh(float x){
  float ax = fabsf(x);
  float t = __expf(-2.0f*ax);
  float r = (1.0f - t)/(1.0f + t);
  return copysignf(r, x);
}
__device__ __forceinline__ unsigned short f2bf(float f){   // round-to-nearest-even
  unsigned int u = __float_as_uint(f);
  unsigned int r = (u + 0x7FFFu + ((u >> 16) & 1u)) >> 16;
  return (unsigned short)r;
}
__device__ __forceinline__ float bf2f(unsigned short u){
  return __uint_as_float(((unsigned)u) << 16);
}

// grid-stride init: enc->bf16 copy; copy h0->harr[0], c0; zero cov, vsum.
__global__ __launch_bounds__(256) void k_init(const float* __restrict__ enc,
    const float* __restrict__ h0, const float* __restrict__ c0,
    unsigned short* __restrict__ enc_bf, float* __restrict__ harr,
    float* __restrict__ cbuf, float* __restrict__ cov, float* __restrict__ vsum){
  const int stride = gridDim.x*256;
  for (int i = blockIdx.x*256 + threadIdx.x; i < B*S*H; i += stride){
    enc_bf[i] = f2bf(enc[i]);
    if (i < B*H){ harr[i] = h0[i]; cbuf[i] = c0[i]; }
    if (i < B*S) cov[i] = 0.0f;
    if (i < T*B) vsum[i] = 0.0f;
  }
}

// x_all[0][b][j] = emb[b][0][:] . W_xctx[j][:E] + b_xctx[j]   (ctx_0 = 0)
__global__ __launch_bounds__(128) void k_x0(const float* __restrict__ emb,
    const float* __restrict__ W_xctx, const float* __restrict__ b_xctx,
    float* __restrict__ x0){
  const int b = blockIdx.x, tid = threadIdx.x;
  __shared__ float se[E];
  se[tid] = emb[(size_t)(b*T)*E + tid];
  __syncthreads();
  const float* w = W_xctx + (size_t)tid*(E+H);
  float acc = b_xctx[tid];
  #pragma unroll 8
  for (int k=0;k<E;k+=4){
    float4 wv = *reinterpret_cast<const float4*>(w+k);
    acc += se[k]*wv.x + se[k+1]*wv.y + se[k+2]*wv.z + se[k+3]*wv.w;
  }
  x0[b*E + tid] = acc;
}

// WdT[a][b] = W_energy[b][a]  (512x512). grid (16,16) x 256.
__global__ __launch_bounds__(256) void k_trw(const float* __restrict__ W_energy,
                                             float* __restrict__ WdT){
  __shared__ float tile[32][33];
  const int j0 = blockIdx.x*32, k0 = blockIdx.y*32;
  const int tx = threadIdx.x & 31, ty = threadIdx.x >> 5;
  #pragma unroll
  for (int r=0;r<4;++r)
    tile[ty+8*r][tx] = W_energy[(size_t)(k0+ty+8*r)*(2*H) + j0 + tx];
  __syncthreads();
  #pragma unroll
  for (int r=0;r<4;++r)
    WdT[(size_t)(j0+ty+8*r)*H + k0 + tx] = tile[tx][ty+8*r];
}

// MFMA enc_proj: encp[m][n] = f2bf( enc[m][:] . W_energy[n][H:] + b_energy[n] ).
// M=6400, N=512, K=512. Grid (4 n-tiles, 25 m-tiles) x 512 (8 waves).
// Block tile 256M x 128N; wave tile 64x64; same fragment layout as k_vocab3.
__global__ __launch_bounds__(512) void k_encproj2(const float* __restrict__ enc,
    const float* __restrict__ W_energy, const float* __restrict__ b_energy,
    unsigned short* __restrict__ enc_proj){
  __shared__ unsigned short ldsA[256][72];
  __shared__ unsigned short ldsB[128][72];
  const int tid = threadIdx.x, lane = tid & 63, w = tid >> 6;
  const int wm = w >> 1, wn = w & 1;
  const int m0 = (int)blockIdx.y * 256;
  const int n0 = (int)blockIdx.x * 128;
  const int nl = lane & 15, kg = lane >> 4;
  f32x4 acc[4][4];
  #pragma unroll
  for (int mf=0;mf<4;++mf)
    #pragma unroll
    for (int nf=0;nf<4;++nf) acc[mf][nf] = (f32x4){0.f,0.f,0.f,0.f};
  for (int kc=0; kc<8; ++kc){
    __syncthreads();
    // stage A: 256 enc rows x 64 k (fp32 -> bf16)
    for (int j = tid; j < 4096; j += 512){
      const int row = j >> 4, c4 = j & 15;
      const float4 v = *reinterpret_cast<const float4*>(
          enc + (size_t)(m0+row)*H + kc*64 + c4*4);
      ushort4 u; u.x=f2bf(v.x); u.y=f2bf(v.y); u.z=f2bf(v.z); u.w=f2bf(v.w);
      *reinterpret_cast<ushort4*>(&ldsA[row][c4*4]) = u;
    }
    // stage B: 128 W_energy rows (cols H..) x 64 k
    for (int j = tid; j < 2048; j += 512){
      const int row = j >> 4, c4 = j & 15;
      const float4 v = *reinterpret_cast<const float4*>(
          W_energy + (size_t)(n0+row)*(2*H) + H + kc*64 + c4*4);
      ushort4 u; u.x=f2bf(v.x); u.y=f2bf(v.y); u.z=f2bf(v.z); u.w=f2bf(v.w);
      *reinterpret_cast<ushort4*>(&ldsB[row][c4*4]) = u;
    }
    __syncthreads();
    #pragma unroll
    for (int kk=0; kk<2; ++kk){
      short8v a[4], bf[4];
      #pragma unroll
      for (int mf=0;mf<4;++mf)
        a[mf] = *reinterpret_cast<const short8v*>(&ldsA[wm*64 + mf*16 + nl][kk*32 + kg*8]);
      #pragma unroll
      for (int nf=0;nf<4;++nf)
        bf[nf] = *reinterpret_cast<const short8v*>(&ldsB[wn*64 + nf*16 + nl][kk*32 + kg*8]);
      #pragma unroll
      for (int mf=0;mf<4;++mf)
        #pragma unroll
        for (int nf=0;nf<4;++nf)
          acc[mf][nf] = __builtin_amdgcn_mfma_f32_16x16x32_bf16(a[mf], bf[nf], acc[mf][nf], 0, 0, 0);
    }
  }
  float bv[4];
  #pragma unroll
  for (int nf=0;nf<4;++nf) bv[nf] = b_energy[n0 + wn*64 + nf*16 + nl];
  #pragma unroll
  for (int mf=0;mf<4;++mf){
    #pragma unroll
    for (int r=0;r<4;++r){
      const int m = m0 + wm*64 + mf*16 + kg*4 + r;
      #pragma unroll
      for (int nf=0;nf<4;++nf){
        const int n = n0 + wn*64 + nf*16 + nl;
        enc_proj[(size_t)m*H + n] = f2bf(acc[mf][nf][r] + bv[nf]);
      }
    }
  }
}

// grid 256 x 256: gates partial GEMM -> gpart[kh][b][row].
__global__ __launch_bounds__(256) void k_gates2(
    const float* __restrict__ x, const float* __restrict__ hold,
    const float* __restrict__ W_ih, const float* __restrict__ W_hh,
    float* __restrict__ gpart){
  const int blk = blockIdx.x, tid = threadIdx.x;
  const int gbh = blk >> 2, kh = blk & 3;
  const int gb = gbh >> 1, bh = gbh & 1, b0 = bh*8;
  __shared__ float xh[8][640];
  __shared__ float sg[4][64][9];
  for (int b=0;b<8;++b)
    for (int k=tid;k<640;k+=256)
      xh[b][k] = (k<E) ? x[(b0+b)*E + k] : hold[(b0+b)*H + (k-E)];
  __syncthreads();
  const int w = tid >> 6, l = tid & 63, g = l >> 4, jj = l & 15;
  const int row = g*H + gb*16 + jj;
  float acc[8];
  #pragma unroll
  for (int b=0;b<8;++b) acc[b]=0.0f;
  const int ks = kh*160 + w*40, ke = ks + 40;
  const int k1 = (ke < 128) ? ke : 128;
  if (ks < 128){
    const float* wr = W_ih + (size_t)row*E;
    for (int k=ks; k<k1; k+=4){
      const float4 wv = *reinterpret_cast<const float4*>(wr + k);
      #pragma unroll
      for (int b=0;b<8;++b){
        const float4 xv = *reinterpret_cast<const float4*>(&xh[b][k]);
        acc[b] += xv.x*wv.x + xv.y*wv.y + xv.z*wv.z + xv.w*wv.w;
      }
    }
  }
  const int k2 = (ks > 128) ? ks : 128;
  if (k2 < ke){
    const float* wr = W_hh + (size_t)row*H - 128;   // wr[k] == W_hh[row][k-128]
    for (int k=k2; k<ke; k+=4){
      const float4 wv = *reinterpret_cast<const float4*>(wr + k);
      #pragma unroll
      for (int b=0;b<8;++b){
        const float4 xv = *reinterpret_cast<const float4*>(&xh[b][k]);
        acc[b] += xv.x*wv.x + xv.y*wv.y + xv.z*wv.z + xv.w*wv.w;
      }
    }
  }
  #pragma unroll
  for (int b=0;b<8;++b) sg[w][l][b] = acc[b];
  __syncthreads();
  for (int i=tid; i<512; i+=256){
    const int l2 = i & 63, b = i >> 6;
    const int g2 = l2 >> 4, j2 = l2 & 15;
    const int row2 = g2*H + gb*16 + j2;
    gpart[((size_t)kh*B + (b0+b))*(4*H) + row2] =
        sg[0][l2][b]+sg[1][l2][b]+sg[2][l2][b]+sg[3][l2][b];
  }
}

// grid 64 x 256: LSTM from gpart (dup-write x8, benign) + dec GEMV slice.
__global__ __launch_bounds__(256) void k_dec2(const float* __restrict__ gpart,
    const float* __restrict__ cold, const float* __restrict__ b_ih,
    const float* __restrict__ b_hh, const float* __restrict__ WdT,
    float* __restrict__ cnew, float* __restrict__ hnew, float* __restrict__ dec){
  const int blk = blockIdx.x, tid = threadIdx.x;
  const int jc = blk >> 3, bp = blk & 7, b0 = bp*2;
  __shared__ float sh[2][H];
  __shared__ float r[4][64][2];
  for (int i=tid; i<2*H; i+=256){
    const int bl = i >> 9, j = i & 511;
    const int b = b0 + bl;
    float gs[4];
    #pragma unroll
    for (int g=0; g<4; ++g){
      const int row = g*H + j;
      float v = b_ih[row] + b_hh[row];
      #pragma unroll
      for (int kh=0; kh<4; ++kh) v += gpart[((size_t)kh*B + b)*(4*H) + row];
      gs[g] = v;
    }
    const float ig = fsig(gs[0]);
    const float fg = fsig(gs[1]);
    const float gg = ftanh(gs[2]);
    const float og = fsig(gs[3]);
    const float cn = fg*cold[b*H + j] + ig*gg;
    const float hn = og*ftanh(cn);
    cnew[b*H + j] = cn;
    hnew[b*H + j] = hn;
    sh[bl][j] = hn;
  }
  __syncthreads();
  const int w = tid >> 6, lane = tid & 63;
  const int j = jc*64 + lane;
  float a0=0.0f, a1=0.0f;
  for (int k=w*128; k<w*128+128; ++k){
    const float wv = WdT[(size_t)k*H + j];
    a0 += sh[0][k]*wv;
    a1 += sh[1][k]*wv;
  }
  r[w][lane][0]=a0; r[w][lane][1]=a1;
  __syncthreads();
  if (tid < 128){
    const int jl = tid & 63, bb = tid >> 6;
    dec[(b0+bb)*H + jc*64 + jl] = r[0][jl][bb]+r[1][jl][bb]+r[2][jl][bb]+r[3][jl][bb];
  }
}

// grid (100, B): one (b,s) per wave; bf16 encp. blockIdx.x==0 zeroes xnext.
__global__ __launch_bounds__(256) void k_score(const float* __restrict__ dec_proj,
    const unsigned short* __restrict__ encp, const float* __restrict__ W_cov,
    const float* __restrict__ v_attn, const float* __restrict__ cov,
    float* __restrict__ score, float* __restrict__ xnext){
  const int b = blockIdx.y;
  if (blockIdx.x==0 && threadIdx.x < E) xnext[b*E + threadIdx.x] = 0.0f;
  const int wave = threadIdx.x >> 6, lane = threadIdx.x & 63;
  const int s = blockIdx.x*4 + wave;
  const float cv = cov[b*S + s];
  const int k0 = lane*8;
  const short8v ev = *reinterpret_cast<const short8v*>(encp + (size_t)(b*S + s)*H + k0);
  const float* dp = dec_proj + b*H;
  float acc = 0.0f;
  #pragma unroll
  for (int u=0;u<8;++u){
    const int k = k0+u;
    acc += ftanh(dp[k] + bf2f((unsigned short)ev[u]) + cv*W_cov[k]) * v_attn[k];
  }
  #pragma unroll
  for (int off=32; off>0; off>>=1) acc += __shfl_down(acc, off);
  if (lane==0) score[b*S + s] = acc;
}

// grid (16 b, 8 hc) x 256: softmax; ctx slice -> ctx_all; xnext split-K atomics.
__global__ __launch_bounds__(256) void k_ctx(const float* __restrict__ score,
    const float* __restrict__ masks, const unsigned short* __restrict__ enc_bf,
    const float* __restrict__ emb, int tnext,
    const float* __restrict__ W_xctx, const float* __restrict__ b_xctx,
    float* __restrict__ cov, float* __restrict__ probs_t,
    float* __restrict__ ctx_t, float* __restrict__ xnext){
  const int b = blockIdx.x, hc = blockIdx.y, tid = threadIdx.x;
  __shared__ float red[256], sp[512], sctx[64], se[E];
  if (tid < E) se[tid] = emb[(size_t)(b*T + tnext)*E + tid];
  const float sc0 = (tid < S)      ? score[b*S + tid]       : -1e30f;
  const float sc1 = (tid+256 < S)  ? score[b*S + tid + 256] : -1e30f;
  red[tid] = fmaxf(sc0, sc1);
  __syncthreads();
  for (int off=128; off>0; off>>=1){ if (tid<off) red[tid]=fmaxf(red[tid],red[tid+off]); __syncthreads(); }
  const float mx = red[0];
  __syncthreads();
  const float e0 = (tid < S)     ? __expf(sc0 - mx) : 0.0f;
  const float e1 = (tid+256 < S) ? __expf(sc1 - mx) : 0.0f;
  red[tid] = e0 + e1;
  __syncthreads();
  for (int off=128; off>0; off>>=1){ if (tid<off) red[tid]+=red[tid+off]; __syncthreads(); }
  const float den = red[0];
  __syncthreads();
  const float p0 = (tid < S)     ? (e0/den)*masks[b*S+tid]     : 0.0f;
  const float p1 = (tid+256 < S) ? (e1/den)*masks[b*S+tid+256] : 0.0f;
  red[tid] = p0 + p1;
  __syncthreads();
  for (int off=128; off>0; off>>=1){ if (tid<off) red[tid]+=red[tid+off]; __syncthreads(); }
  const float inv = 1.0f/(red[0] + 1e-12f);
  __syncthreads();
  const float pr0 = p0*inv, pr1 = p1*inv;
  sp[tid] = pr0; sp[tid+256] = pr1;
  if (hc==0){
    if (tid < S){ probs_t[b*S+tid] = pr0; cov[b*S+tid] += pr0; }
    if (tid+256 < S){ probs_t[b*S+tid+256] = pr1; cov[b*S+tid+256] += pr1; }
  }
  __syncthreads();
  {
    const int c = tid & 63, sg_ = tid >> 6;
    const unsigned short* eb = enc_bf + (size_t)b*S*H + hc*64 + c;
    float a = 0.0f;
    for (int s=sg_; s<S; s+=4) a += sp[s]*bf2f(eb[(size_t)s*H]);
    red[tid] = a;
    __syncthreads();
    if (tid < 64){
      const float cval = red[tid]+red[tid+64]+red[tid+128]+red[tid+192];
      sctx[tid] = cval;
      ctx_t[b*H + hc*64 + tid] = cval;
    }
  }
  __syncthreads();
  if (tid < E){
    const float* wr = W_xctx + (size_t)tid*(E+H);
    float acc = 0.0f;
    #pragma unroll
    for (int k=0;k<64;k+=4){
      const float4 wc = *reinterpret_cast<const float4*>(wr + E + hc*64 + k);
      acc += sctx[k]*wc.x + sctx[k+1]*wc.y + sctx[k+2]*wc.z + sctx[k+3]*wc.w;
    }
    #pragma unroll
    for (int k=0;k<16;k+=4){
      const float4 we = *reinterpret_cast<const float4*>(wr + hc*16 + k);
      const float* eb2 = se + hc*16 + k;
      acc += eb2[0]*we.x + eb2[1]*we.y + eb2[2]*we.z + eb2[3]*we.w;
    }
    if (hc==0) acc += b_xctx[tid];
    atomicAdd(&xnext[b*E + tid], acc);
  }
}

// MFMA GEMM: hh_all[m][n] = [h(m) | ctx(m)] . W_ad[n][:] + b_ad[n].
// Grid (8 nt, 4 mt) x 512; block tile 128M x 64N; wave tile 64M x 16N.
__global__ __launch_bounds__(512) void k_hhgemm(const float* __restrict__ harr,
    const float* __restrict__ ctx_all, const float* __restrict__ W_ad,
    const float* __restrict__ b_ad, float* __restrict__ hh_all){
  __shared__ unsigned short ldsA[128][72];
  __shared__ unsigned short ldsB[64][72];
  const int tid = threadIdx.x, lane = tid & 63, w = tid >> 6;
  const int wm = w >> 2, wn = w & 3;
  const int m0 = (int)blockIdx.y * 128;
  const int n0 = (int)blockIdx.x * 64;
  const int nl = lane & 15, kg = lane >> 4;
  f32x4 acc[4];
  #pragma unroll
  for (int mf=0;mf<4;++mf) acc[mf] = (f32x4){0.f,0.f,0.f,0.f};
  for (int kc=0; kc<16; ++kc){
    __syncthreads();
    for (int j = tid; j < 2048; j += 512){
      const int row = j >> 4, c4 = j & 15;
      const int kk_ = kc*64 + c4*4;
      const float* src = (kk_ < H)
        ? (harr + (size_t)(m0+row+B)*H + kk_)
        : (ctx_all + (size_t)(m0+row)*H + (kk_ - H));
      const float4 v = *reinterpret_cast<const float4*>(src);
      ushort4 u; u.x=f2bf(v.x); u.y=f2bf(v.y); u.z=f2bf(v.z); u.w=f2bf(v.w);
      *reinterpret_cast<ushort4*>(&ldsA[row][c4*4]) = u;
    }
    for (int j = tid; j < 1024; j += 512){
      const int row = j >> 4, c4 = j & 15;
      const float4 v = *reinterpret_cast<const float4*>(
          W_ad + (size_t)(n0+row)*(2*H) + kc*64 + c4*4);
      ushort4 u; u.x=f2bf(v.x); u.y=f2bf(v.y); u.z=f2bf(v.z); u.w=f2bf(v.w);
      *reinterpret_cast<ushort4*>(&ldsB[row][c4*4]) = u;
    }
    __syncthreads();
    #pragma unroll
    for (int kk=0; kk<2; ++kk){
      const short8v bfr = *reinterpret_cast<const short8v*>(&ldsB[wn*16 + nl][kk*32 + kg*8]);
      #pragma unroll
      for (int mf=0;mf<4;++mf){
        const short8v a = *reinterpret_cast<const short8v*>(&ldsA[wm*64 + mf*16 + nl][kk*32 + kg*8]);
        acc[mf] = __builtin_amdgcn_mfma_f32_16x16x32_bf16(a, bfr, acc[mf], 0, 0, 0);
      }
    }
  }
  const int n = n0 + wn*16 + nl;
  const float bv = b_ad[n];
  #pragma unroll
  for (int mf=0;mf<4;++mf){
    #pragma unroll
    for (int r=0;r<4;++r){
      const int m = m0 + wm*64 + mf*16 + kg*4 + r;
      hh_all[(size_t)m*H + n] = acc[mf][r] + bv;
    }
  }
}

// praw[m] = [ctx(m), h(m), x(m)] . W_pgen + b_pgen. grid 128 x 256 (one m/wave).
__global__ __launch_bounds__(256) void k_pgen(const float* __restrict__ ctx_all,
    const float* __restrict__ harr, const float* __restrict__ x_all,
    const float* __restrict__ W_pgen, const float* __restrict__ b_pgen,
    float* __restrict__ praw){
  const int m = blockIdx.x*4 + (threadIdx.x >> 6);
  const int lane = threadIdx.x & 63;
  float part = 0.0f;
  for (int k = lane; k < 2*H+E; k += 64){
    float v;
    if (k < H)        v = ctx_all[(size_t)m*H + k];
    else if (k < 2*H) v = harr[(size_t)(m+B)*H + (k-H)];
    else              v = x_all[(size_t)m*E + (k-2*H)];
    part += v * W_pgen[k];
  }
  #pragma unroll
  for (int off=32; off>0; off>>=1) part += __shfl_down(part, off);
  if (lane==0) praw[m] = part + b_pgen[0];
}

// Canonical LDS-tiled MFMA GEMM: out = exp(hh . W_vocab^T + b), rowsums -> vsum.
__global__ __launch_bounds__(512) void k_vocab3(
    const float* __restrict__ hh_all,
    const float* __restrict__ W_vocab, const float* __restrict__ b_vocab,
    float* __restrict__ out, float* __restrict__ vsum){
  __shared__ unsigned short ldsA[256][72];
  __shared__ unsigned short ldsB[128][72];
  __shared__ float svs[256];
  const int tid = threadIdx.x, lane = tid & 63, w = tid >> 6;
  const int wm = w >> 1, wn = w & 1;
  const int m0 = (int)blockIdx.y * 256;
  const int n0 = (int)blockIdx.x * 128;
  const int nl = lane & 15, kg = lane >> 4;
  if (tid < 256) svs[tid] = 0.0f;
  f32x4 acc[4][4];
  #pragma unroll
  for (int mf=0;mf<4;++mf)
    #pragma unroll
    for (int nf=0;nf<4;++nf) acc[mf][nf] = (f32x4){0.f,0.f,0.f,0.f};
  for (int kc=0; kc<8; ++kc){
    __syncthreads();
    for (int j = tid; j < 4096; j += 512){
      const int row = j >> 4, c4 = j & 15;
      const float4 v = *reinterpret_cast<const float4*>(
          hh_all + (size_t)(m0+row)*H + kc*64 + c4*4);
      ushort4 u; u.x=f2bf(v.x); u.y=f2bf(v.y); u.z=f2bf(v.z); u.w=f2bf(v.w);
      *reinterpret_cast<ushort4*>(&ldsA[row][c4*4]) = u;
    }
    for (int j = tid; j < 2048; j += 512){
      const int row = j >> 4, c4 = j & 15;
      const float4 v = *reinterpret_cast<const float4*>(
          W_vocab + (size_t)(n0+row)*H + kc*64 + c4*4);
      ushort4 u; u.x=f2bf(v.x); u.y=f2bf(v.y); u.z=f2bf(v.z); u.w=f2bf(v.w);
      *reinterpret_cast<ushort4*>(&ldsB[row][c4*4]) = u;
    }
    __syncthreads();
    #pragma unroll
    for (int kk=0; kk<2; ++kk){
      short8v a[4], bf[4];
      #pragma unroll
      for (int mf=0;mf<4;++mf)
        a[mf] = *reinterpret_cast<const short8v*>(&ldsA[wm*64 + mf*16 + nl][kk*32 + kg*8]);
      #pragma unroll
      for (int nf=0;nf<4;++nf)
        bf[nf] = *reinterpret_cast<const short8v*>(&ldsB[wn*64 + nf*16 + nl][kk*32 + kg*8]);
      #pragma unroll
      for (int mf=0;mf<4;++mf)
        #pragma unroll
        for (int nf=0;nf<4;++nf)
          acc[mf][nf] = __builtin_amdgcn_mfma_f32_16x16x32_bf16(a[mf], bf[nf], acc[mf][nf], 0, 0, 0);
    }
  }
  float bv[4];
  #pragma unroll
  for (int nf=0;nf<4;++nf) bv[nf] = b_vocab[n0 + wn*64 + nf*16 + nl];
  #pragma unroll
  for (int mf=0;mf<4;++mf){
    #pragma unroll
    for (int r=0;r<4;++r){
      const int m = m0 + wm*64 + mf*16 + kg*4 + r;   // m = t*16 + b
      const int tq = m >> 4, bq = m & 15;
      float* orow = out + ((size_t)bq*T + tq)*VEXT;
      float s = 0.0f;
      #pragma unroll
      for (int nf=0;nf<4;++nf){
        const int n = n0 + wn*64 + nf*16 + nl;
        const float e = __expf(acc[mf][nf][r] + bv[nf]);
        orow[n] = e;
        s += e;
      }
      s += __shfl_xor(s, 1);
      s += __shfl_xor(s, 2);
      s += __shfl_xor(s, 4);
      s += __shfl_xor(s, 8);
      if (nl == 0) atomicAdd(&svs[m - m0], s);
    }
  }
  __syncthreads();
  for (int i = tid; i < 256; i += 512) atomicAdd(&vsum[m0 + i], svs[i]);
}

__global__ __launch_bounds__(256) void k_finalize(const float* __restrict__ praw,
    const float* __restrict__ vsum, const float* __restrict__ exz,
    float* __restrict__ out){
  const int rm = blockIdx.x, vc = blockIdx.y, tid = threadIdx.x;
  const int t = rm >> 4, b = rm & 15;
  float* orow = out + ((size_t)b*T + t)*VEXT;
  if (vc < 8){
    const float scl = fsig(praw[rm]) / vsum[rm];
    const int base = vc*4000;
    for (int i = tid; i < 4000; i += 256) orow[base + i] *= scl;
  } else if (tid < OOV){
    orow[V + tid] = exz[b*OOV + tid];
  }
}

__global__ __launch_bounds__(256) void k_scatter_all(const float* __restrict__ probs_all,
    const float* __restrict__ praw, const int* __restrict__ eidx,
    float* __restrict__ out){
  const int stride = gridDim.x*256;
  for (int i = blockIdx.x*256 + threadIdx.x; i < T*B*S; i += stride){
    const int t = i / (B*S);
    const int rem = i - t*B*S;
    const int b = rem / S, s = rem - b*S;
    const float fac = 1.0f - fsig(praw[t*B + b]);
    float* orow = out + ((size_t)b*T + t)*VEXT;
    atomicAdd(&orow[eidx[b*S + s]], fac*probs_all[(size_t)(t*B + b)*S + s]);
  }
}

} // namespace

extern "C" void kernel_launch(void* const* d_in, const int* in_sizes, int n_in,
                              void* d_out, int out_size, void* d_ws, size_t ws_size,
                              hipStream_t stream){
  const float* emb    = (const float*)d_in[0];
  const float* h0     = (const float*)d_in[1];
  const float* c0     = (const float*)d_in[2];
  const float* enc    = (const float*)d_in[3];
  const float* masks  = (const float*)d_in[4];
  const float* exz    = (const float*)d_in[5];
  const int*   eidx   = (const int*)d_in[6];
  const float* W_ih   = (const float*)d_in[7];
  const float* W_hh   = (const float*)d_in[8];
  const float* b_ih   = (const float*)d_in[9];
  const float* b_hh   = (const float*)d_in[10];
  const float* W_vocab= (const float*)d_in[11];
  const float* b_vocab= (const float*)d_in[12];
  const float* W_cov  = (const float*)d_in[13];
  const float* W_energy=(const float*)d_in[14];
  const float* b_energy=(const float*)d_in[15];
  const float* v_attn = (const float*)d_in[16];
  const float* W_xctx = (const float*)d_in[17];
  const float* b_xctx = (const float*)d_in[18];
  const float* W_ad   = (const float*)d_in[19];
  const float* b_ad   = (const float*)d_in[20];
  const float* W_pgen = (const float*)d_in[21];
  const float* b_pgen = (const float*)d_in[22];

  float* ws = (float*)d_ws;
  float* cbuf     = ws;                 // 2 x 8192            -> 16384
  float* x_all    = ws + 16384;         // 33 x 2048 = 67584   -> 83968
  float* dec      = ws + 83968;         // 8192                -> 92160
  float* score    = ws + 92160;         // 6400                -> 98560
  float* cov      = ws + 98560;         // 6400                -> 104960
  float* praw     = ws + 104960;        // 512                 -> 105472
  float* vsum     = ws + 105472;        // 512                 -> 105984
  float* probs_all= ws + 105984;        // 204800              -> 310784
  float* harr     = ws + 310784;        // 33 x 8192 = 270336  -> 581120
  float* ctx_all  = ws + 581120;        // 262144              -> 843264
  float* hh_all   = ws + 843264;        // 262144              -> 1105408
  float* WdT      = ws + 1105408;       // 262144              -> 1367552
  float* gpart    = ws + 1367552;       // 131072              -> 1498624
  unsigned short* enc_bf = (unsigned short*)(ws + 1498624);   // 3276800 u16
  unsigned short* encp   = (unsigned short*)(ws + 3137024);   // 3276800 u16
  float* outp     = (float*)d_out;

  k_init<<<300,256,0,stream>>>(enc,h0,c0,enc_bf,harr,cbuf,cov,vsum);
  k_x0<<<16,128,0,stream>>>(emb,W_xctx,b_xctx,x_all);
  k_trw<<<dim3(16,16),256,0,stream>>>(W_energy,WdT);
  k_encproj2<<<dim3(4,25),512,0,stream>>>(enc,W_energy,b_energy,encp);

  for (int t=0;t<T;++t){
    const int p = t&1;
    const float* cold = cbuf + p*8192;
    float* cnew = cbuf + (p^1)*8192;
    const int tnext = (t+1 < T) ? (t+1) : (T-1);
    k_gates2<<<256,256,0,stream>>>(x_all + (size_t)t*B*E, harr + (size_t)t*B*H,
                                   W_ih, W_hh, gpart);
    k_dec2<<<64,256,0,stream>>>(gpart, cold, b_ih, b_hh, WdT,
                                cnew, harr + (size_t)(t+1)*B*H, dec);
    k_score<<<dim3(100,16),256,0,stream>>>(dec, encp, W_cov, v_attn, cov, score,
                                           x_all + (size_t)(t+1)*B*E);
    k_ctx<<<dim3(16,8),256,0,stream>>>(score, masks, enc_bf, emb, tnext,
        W_xctx, b_xctx, cov, probs_all + (size_t)t*B*S,
        ctx_all + (size_t)t*B*H, x_all + (size_t)(t+1)*B*E);
  }

  k_hhgemm<<<dim3(8,4),512,0,stream>>>(harr, ctx_all, W_ad, b_ad, hh_all);
  k_pgen<<<128,256,0,stream>>>(ctx_all, harr, x_all, W_pgen, b_pgen, praw);
  k_vocab3<<<dim3(250,2),512,0,stream>>>(hh_all, W_vocab, b_vocab, outp, vsum);
  k_finalize<<<dim3(512,9),256,0,stream>>>(praw, vsum, exz, outp);
  k_scatter_all<<<200,256,0,stream>>>(probs_all, praw, eidx, outp);
}